// Round 4
// baseline (300.232 us; speedup 1.0000x reference)
//
#include <hip/hip_runtime.h>
#include <hip/hip_bf16.h>

namespace {

constexpr int B_   = 4;
constexpr int CIN  = 64;
constexpr int COUT = 128;
constexpr int HIN  = 64,  WIN  = 1024;
constexpr int HOUT = 32,  WOUT = 512;
constexpr int TW   = 16;        // wo positions per block
constexpr int SP   = 1096;      // per-position S stride in bf16 elems (2192 B = 137 chunks, 137%8==1)
constexpr int KTOT = CIN * 16;  // 1024

typedef __bf16 bf16x8 __attribute__((ext_vector_type(8)));
typedef float  f32x4  __attribute__((ext_vector_type(4)));

// ---------------- prep: weights ----------------
// wcb[o][tap*64+c] = Wc[o][c*16+tap] (bf16);  w2t[c][c1] = W2[c1][c] (bf16)
__global__ void cvt_wts(const float* __restrict__ Wc, const float* __restrict__ W2,
                        __hip_bfloat16* __restrict__ wcb, __hip_bfloat16* __restrict__ w2t) {
    int i = blockIdx.x * 256 + threadIdx.x;
    if (i < COUT * KTOT) {
        int o = i >> 10, k = i & 1023, tap = k >> 6, c = k & 63;
        wcb[i] = __float2bfloat16(Wc[(size_t)o * KTOT + c * 16 + tap]);
    } else if (i < COUT * KTOT + CIN * CIN) {
        int m = i - COUT * KTOT;
        int c = m >> 6, c1 = m & 63;
        w2t[m] = __float2bfloat16(W2[c1 * CIN + c]);
    }
}

// ---------------- prep: x -> xT[b,h,w,c] bf16 ----------------
__global__ __launch_bounds__(256)
void prep_xt(const float* __restrict__ x, __hip_bfloat16* __restrict__ xT) {
    __shared__ float tile[CIN][65];
    const int bx = blockIdx.x;          // b*1024 + h*16 + wt
    const int wt = bx & 15;
    const int h  = (bx >> 4) & 63;
    const int b  = bx >> 10;
    const int w0 = wt * 64;
    const int t  = threadIdx.x;

    const int wl = t & 63;
    const int c0 = (t >> 6) * 16;
    #pragma unroll
    for (int cc = 0; cc < 16; ++cc) {
        const int c = c0 + cc;
        tile[c][wl] = x[(((size_t)b*CIN + c)*HIN + h)*WIN + w0 + wl];
    }
    __syncthreads();

    const int wl2 = t >> 2;
    const int cq  = (t & 3) * 16;
    __align__(16) unsigned short pack[16];
    #pragma unroll
    for (int cc = 0; cc < 16; ++cc) {
        __hip_bfloat16 v = __float2bfloat16(tile[cq + cc][wl2]);
        pack[cc] = *reinterpret_cast<unsigned short*>(&v);
    }
    uint4* dst = reinterpret_cast<uint4*>(
        xT + ((size_t)(b*HIN + h)*WIN + w0 + wl2)*CIN + cq);
    dst[0] = *reinterpret_cast<uint4*>(&pack[0]);
    dst[1] = *reinterpret_cast<uint4*>(&pack[8]);
}

// ---------------- main (xT path) ----------------
__global__ __launch_bounds__(256, 4)
void fused_main(const float* __restrict__ r,
                const float* __restrict__ W1, const float* __restrict__ b1,
                const __hip_bfloat16* __restrict__ W2T, const float* __restrict__ b2,
                const __hip_bfloat16* __restrict__ WcB, const float* __restrict__ bc,
                const __hip_bfloat16* __restrict__ xT,
                float* __restrict__ out)
{
    __shared__ __hip_bfloat16 S[TW * SP];   // 35,072 B; per-p: w[tap][c] (stride 68) then A chunks

    const int t   = threadIdx.x;
    const int bx  = blockIdx.x;
    const int wt  = bx & 31;
    const int ho  = (bx >> 5) & 31;
    const int b   = bx >> 10;
    const int wo0 = wt * TW;

    const float* rb = r + (size_t)b * HIN * WIN;

    if (t < TW) {
        const int wo = wo0 + t;
        out[(size_t)B_*COUT*HOUT*WOUT + ((size_t)b*HOUT + ho)*WOUT + wo] =
            rb[(2*ho + 1)*WIN + (2*wo + 1)];
    }

    const int ln   = t & 63;
    const int wv   = t >> 6;
    const int lm   = ln & 15;
    const int quad = ln >> 4;

    const float AZI = 0.006135923151542565f;  // 2*pi/1024
    const float INC = 0.0073f;

    // ============ phase 1b: w = leaky(pe@W1+b1)@W2 + b2 via MFMA ============
    {
        bf16x8 bfr[4][2];
        float  b2v[4];
        #pragma unroll
        for (int nt = 0; nt < 4; ++nt) {
            #pragma unroll
            for (int ks = 0; ks < 2; ++ks)
                bfr[nt][ks] = *reinterpret_cast<const bf16x8*>(
                    W2T + (nt*16 + lm)*CIN + ks*32 + quad*8);
            b2v[nt] = b2[nt*16 + lm];
        }

        const int i_ = lm >> 2, j_ = lm & 3;
        const float di = (float)(i_ - 2), dj = (float)(j_ - 2);
        const float cA = cosf(AZI * dj), sA = sinf(AZI * dj);
        const float cI = cosf(INC * di), sI = sinf(INC * di);
        const int hsrc = (2*ho + j_ + 63) & 63;

        #pragma unroll
        for (int mt = 0; mt < 4; ++mt) {
            const int p  = wv*4 + mt;
            const int wo = wo0 + p;
            const int wsrc = 2*wo + i_ - 1;
            const bool inb = (unsigned)wsrc < (unsigned)WIN;
            const float rpv = inb ? rb[hsrc*WIN + wsrc] : 100.0f;
            const float rc  = rb[(2*ho + 1)*WIN + (2*wo + 1)];
            const float pe0 = rpv * cA * cI - rc;
            const float pe1 = rpv * cA * sI;
            const float pe2 = rpv * sA;

            bf16x8 af0, af1;
            #pragma unroll
            for (int ks = 0; ks < 2; ++ks) {
                const int cb = ks*32 + quad*8;
                #pragma unroll
                for (int j = 0; j < 8; ++j) {
                    const int c1 = cb + j;
                    float hv = fmaf(pe0, W1[c1],
                               fmaf(pe1, W1[CIN + c1],
                               fmaf(pe2, W1[2*CIN + c1], b1[c1])));
                    hv = (hv >= 0.0f) ? hv : 0.2f * hv;
                    __hip_bfloat16 hb = __float2bfloat16(hv);
                    if (ks == 0) af0[j] = *reinterpret_cast<__bf16*>(&hb);
                    else         af1[j] = *reinterpret_cast<__bf16*>(&hb);
                }
            }

            #pragma unroll
            for (int nt = 0; nt < 4; ++nt) {
                f32x4 acc = {b2v[nt], b2v[nt], b2v[nt], b2v[nt]};
                acc = __builtin_amdgcn_mfma_f32_16x16x32_bf16(af0, bfr[nt][0], acc, 0, 0, 0);
                acc = __builtin_amdgcn_mfma_f32_16x16x32_bf16(af1, bfr[nt][1], acc, 0, 0, 0);
                #pragma unroll
                for (int q = 0; q < 4; ++q)
                    S[p*SP + (quad*4 + q)*68 + nt*16 + lm] = __float2bfloat16(acc[q]);
            }
        }
    }

    // ============ phase 1c: A[p][kc=tap*8+g] = w * xT  (swizzled chunk write) ============
    {
        const int p   = t >> 4;
        const int tap = t & 15;
        const int i_  = tap >> 2, j_ = tap & 3;
        const int hsrc = (2*ho + j_ + 63) & 63;
        const int wo   = wo0 + p;
        const int wsrc = 2*wo + i_ - 1;
        const bool inb = (unsigned)wsrc < (unsigned)WIN;

        const __hip_bfloat16* xrow =
            xT + ((size_t)(b*HIN + hsrc)*WIN + (inb ? wsrc : 0))*CIN;

        uint4 xv[8];
        #pragma unroll
        for (int g = 0; g < 8; ++g)
            xv[g] = inb ? reinterpret_cast<const uint4*>(xrow)[g]
                        : make_uint4(0u,0u,0u,0u);

        uint2 wrow[16];
        const uint2* wp = reinterpret_cast<const uint2*>(S + p*SP + tap*68);
        #pragma unroll
        for (int u = 0; u < 16; ++u) wrow[u] = wp[u];

        uint4* Ap = reinterpret_cast<uint4*>(S + (size_t)p*SP);
        #pragma unroll
        for (int g = 0; g < 8; ++g) {
            uint pk[4];
            const unsigned short* xs = reinterpret_cast<const unsigned short*>(&xv[g]);
            #pragma unroll
            for (int pr = 0; pr < 4; ++pr) {
                const int c0 = g*8 + pr*2;
                const uint2 wv2 = wrow[c0 >> 2];
                const uint word = (c0 & 2) ? wv2.y : wv2.x;
                const float w0f = __uint_as_float(word << 16);
                const float w1f = __uint_as_float(word & 0xffff0000u);
                const float x0f = __uint_as_float(((uint)xs[pr*2])   << 16);
                const float x1f = __uint_as_float(((uint)xs[pr*2+1]) << 16);
                __hip_bfloat16 p0 = __float2bfloat16(w0f * x0f);
                __hip_bfloat16 p1 = __float2bfloat16(w1f * x1f);
                pk[pr] = (uint)*reinterpret_cast<unsigned short*>(&p0)
                       | ((uint)*reinterpret_cast<unsigned short*>(&p1) << 16);
            }
            const int pc = tap*8 + (g ^ (tap & 7));   // XOR-swizzled 16B-chunk index
            Ap[pc] = make_uint4(pk[0], pk[1], pk[2], pk[3]);
        }
    }

    __syncthreads();

    // ============ phase 2: out[o][p] = bc[o] + sum_k Wc[o][k]*A[p][k] ============
    {
        const int o0 = wv * 32;
        const __hip_bfloat16* wcP0 = WcB + ((size_t)(o0 + lm)) * KTOT + quad*8;
        const __hip_bfloat16* wcP1 = wcP0 + (size_t)16 * KTOT;
        const __hip_bfloat16* aBase = S + lm*SP;

        f32x4 acc0 = {0.f,0.f,0.f,0.f};
        f32x4 acc1 = {0.f,0.f,0.f,0.f};

        #pragma unroll 4
        for (int ks = 0; ks < KTOT/32; ++ks) {
            // logical chunk kc = 4*ks + quad; phys = (kc&~7) | ((kc&7)^((kc>>3)&7))
            const int s    = (ks >> 1) & 7;
            const int phys = 8*(ks >> 1) + ((4*(ks & 1) + quad) ^ s);
            const bf16x8 af = *reinterpret_cast<const bf16x8*>(aBase + phys*8);
            const bf16x8 w0 = *reinterpret_cast<const bf16x8*>(wcP0 + ks*32);
            const bf16x8 w1 = *reinterpret_cast<const bf16x8*>(wcP1 + ks*32);
            acc0 = __builtin_amdgcn_mfma_f32_16x16x32_bf16(w0, af, acc0, 0, 0, 0);
            acc1 = __builtin_amdgcn_mfma_f32_16x16x32_bf16(w1, af, acc1, 0, 0, 0);
        }

        #pragma unroll
        for (int q = 0; q < 4; ++q) {
            const int oa = o0 + quad*4 + q;
            const int ob = oa + 16;
            out[(((size_t)b*COUT + oa)*HOUT + ho)*WOUT + wo0 + lm] = acc0[q] + bc[oa];
            out[(((size_t)b*COUT + ob)*HOUT + ho)*WOUT + wo0 + lm] = acc1[q] + bc[ob];
        }
    }
}

// ---------------- fallback main (round-3 path, x fp32 from global) ----------------
__global__ __launch_bounds__(256, 3)
void fused_fb(const float* __restrict__ x,  const float* __restrict__ r,
              const float* __restrict__ W1, const float* __restrict__ b1,
              const __hip_bfloat16* __restrict__ W2T, const float* __restrict__ b2,
              const __hip_bfloat16* __restrict__ WcB, const float* __restrict__ bc,
              float* __restrict__ out)
{
    __shared__ __hip_bfloat16 S[TW * SP];

    const int t   = threadIdx.x;
    const int bx  = blockIdx.x;
    const int wt  = bx & 31;
    const int ho  = (bx >> 5) & 31;
    const int b   = bx >> 10;
    const int wo0 = wt * TW;

    const float* rb = r + (size_t)b * HIN * WIN;

    if (t < TW) {
        const int wo = wo0 + t;
        out[(size_t)B_*COUT*HOUT*WOUT + ((size_t)b*HOUT + ho)*WOUT + wo] =
            rb[(2*ho + 1)*WIN + (2*wo + 1)];
    }

    const int ln   = t & 63;
    const int wv   = t >> 6;
    const int lm   = ln & 15;
    const int quad = ln >> 4;

    const float AZI = 0.006135923151542565f;
    const float INC = 0.0073f;

    {
        bf16x8 bfr[4][2];
        float  b2v[4];
        #pragma unroll
        for (int nt = 0; nt < 4; ++nt) {
            #pragma unroll
            for (int ks = 0; ks < 2; ++ks)
                bfr[nt][ks] = *reinterpret_cast<const bf16x8*>(
                    W2T + (nt*16 + lm)*CIN + ks*32 + quad*8);
            b2v[nt] = b2[nt*16 + lm];
        }
        const int i_ = lm >> 2, j_ = lm & 3;
        const float di = (float)(i_ - 2), dj = (float)(j_ - 2);
        const float cA = cosf(AZI * dj), sA = sinf(AZI * dj);
        const float cI = cosf(INC * di), sI = sinf(INC * di);
        const int hsrc = (2*ho + j_ + 63) & 63;

        #pragma unroll
        for (int mt = 0; mt < 4; ++mt) {
            const int p  = wv*4 + mt;
            const int wo = wo0 + p;
            const int wsrc = 2*wo + i_ - 1;
            const bool inb = (unsigned)wsrc < (unsigned)WIN;
            const float rpv = inb ? rb[hsrc*WIN + wsrc] : 100.0f;
            const float rc  = rb[(2*ho + 1)*WIN + (2*wo + 1)];
            const float pe0 = rpv * cA * cI - rc;
            const float pe1 = rpv * cA * sI;
            const float pe2 = rpv * sA;

            bf16x8 af0, af1;
            #pragma unroll
            for (int ks = 0; ks < 2; ++ks) {
                const int cb = ks*32 + quad*8;
                #pragma unroll
                for (int j = 0; j < 8; ++j) {
                    const int c1 = cb + j;
                    float hv = fmaf(pe0, W1[c1],
                               fmaf(pe1, W1[CIN + c1],
                               fmaf(pe2, W1[2*CIN + c1], b1[c1])));
                    hv = (hv >= 0.0f) ? hv : 0.2f * hv;
                    __hip_bfloat16 hb = __float2bfloat16(hv);
                    if (ks == 0) af0[j] = *reinterpret_cast<__bf16*>(&hb);
                    else         af1[j] = *reinterpret_cast<__bf16*>(&hb);
                }
            }
            #pragma unroll
            for (int nt = 0; nt < 4; ++nt) {
                f32x4 acc = {b2v[nt], b2v[nt], b2v[nt], b2v[nt]};
                acc = __builtin_amdgcn_mfma_f32_16x16x32_bf16(af0, bfr[nt][0], acc, 0, 0, 0);
                acc = __builtin_amdgcn_mfma_f32_16x16x32_bf16(af1, bfr[nt][1], acc, 0, 0, 0);
                #pragma unroll
                for (int q = 0; q < 4; ++q)
                    S[p*SP + (quad*4 + q)*68 + nt*16 + lm] = __float2bfloat16(acc[q]);
            }
        }
    }

    {
        const int p   = t >> 4;
        const int tap = t & 15;
        const int i_  = tap >> 2, j_ = tap & 3;
        const int hsrc = (2*ho + j_ + 63) & 63;
        const int wo   = wo0 + p;
        const int wsrc = 2*wo + i_ - 1;
        const bool inb = (unsigned)wsrc < (unsigned)WIN;

        uint2 wrow[16];
        const uint2* wp = reinterpret_cast<const uint2*>(S + p*SP + tap*68);
        #pragma unroll
        for (int u = 0; u < 16; ++u) wrow[u] = wp[u];

        const float* xb = x + (size_t)b*CIN*HIN*WIN + hsrc*WIN + wsrc;
        uint4* Ap = reinterpret_cast<uint4*>(S + (size_t)p*SP);
        #pragma unroll
        for (int g = 0; g < 8; ++g) {
            uint pk[4];
            #pragma unroll
            for (int pr = 0; pr < 4; ++pr) {
                const int c0 = g*8 + pr*2;
                const uint2 wv2 = wrow[c0 >> 2];
                const uint word = (c0 & 2) ? wv2.y : wv2.x;
                const float w0f = __uint_as_float(word << 16);
                const float w1f = __uint_as_float(word & 0xffff0000u);
                const float x0f = inb ? xb[(size_t)(c0    ) * HIN * WIN] : 0.0f;
                const float x1f = inb ? xb[(size_t)(c0 + 1) * HIN * WIN] : 0.0f;
                __hip_bfloat16 p0 = __float2bfloat16(w0f * x0f);
                __hip_bfloat16 p1 = __float2bfloat16(w1f * x1f);
                pk[pr] = (uint)*reinterpret_cast<unsigned short*>(&p0)
                       | ((uint)*reinterpret_cast<unsigned short*>(&p1) << 16);
            }
            const int pc = tap*8 + (g ^ (tap & 7));
            Ap[pc] = make_uint4(pk[0], pk[1], pk[2], pk[3]);
        }
    }

    __syncthreads();

    {
        const int o0 = wv * 32;
        const __hip_bfloat16* wcP0 = WcB + ((size_t)(o0 + lm)) * KTOT + quad*8;
        const __hip_bfloat16* wcP1 = wcP0 + (size_t)16 * KTOT;
        const __hip_bfloat16* aBase = S + lm*SP;

        f32x4 acc0 = {0.f,0.f,0.f,0.f};
        f32x4 acc1 = {0.f,0.f,0.f,0.f};

        #pragma unroll 4
        for (int ks = 0; ks < KTOT/32; ++ks) {
            const int s    = (ks >> 1) & 7;
            const int phys = 8*(ks >> 1) + ((4*(ks & 1) + quad) ^ s);
            const bf16x8 af = *reinterpret_cast<const bf16x8*>(aBase + phys*8);
            const bf16x8 w0 = *reinterpret_cast<const bf16x8*>(wcP0 + ks*32);
            const bf16x8 w1 = *reinterpret_cast<const bf16x8*>(wcP1 + ks*32);
            acc0 = __builtin_amdgcn_mfma_f32_16x16x32_bf16(w0, af, acc0, 0, 0, 0);
            acc1 = __builtin_amdgcn_mfma_f32_16x16x32_bf16(w1, af, acc1, 0, 0, 0);
        }

        #pragma unroll
        for (int q = 0; q < 4; ++q) {
            const int oa = o0 + quad*4 + q;
            const int ob = oa + 16;
            out[(((size_t)b*COUT + oa)*HOUT + ho)*WOUT + wo0 + lm] = acc0[q] + bc[oa];
            out[(((size_t)b*COUT + ob)*HOUT + ho)*WOUT + wo0 + lm] = acc1[q] + bc[ob];
        }
    }
}

} // namespace

extern "C" void kernel_launch(void* const* d_in, const int* in_sizes, int n_in,
                              void* d_out, int out_size, void* d_ws, size_t ws_size,
                              hipStream_t stream) {
    const float* x  = (const float*)d_in[0];
    const float* r  = (const float*)d_in[1];
    const float* W1 = (const float*)d_in[2];
    const float* b1 = (const float*)d_in[3];
    const float* W2 = (const float*)d_in[4];
    const float* b2 = (const float*)d_in[5];
    const float* Wc = (const float*)d_in[6];
    const float* bc = (const float*)d_in[7];
    float* out = (float*)d_out;

    __hip_bfloat16* wcb = (__hip_bfloat16*)d_ws;                       // 256 KB
    __hip_bfloat16* w2t = (__hip_bfloat16*)((char*)d_ws + 262144);     // 8 KB
    __hip_bfloat16* xTp = (__hip_bfloat16*)((char*)d_ws + 524288);     // 32 MB

    const size_t XT_BYTES = (size_t)B_ * HIN * WIN * CIN * 2;
    const bool use_xt = ws_size >= 524288 + XT_BYTES;

    const int ntot = COUT*KTOT + CIN*CIN;
    hipLaunchKernelGGL(cvt_wts, dim3((ntot + 255)/256), dim3(256), 0, stream,
                       Wc, W2, wcb, w2t);

    dim3 grid(B_ * HOUT * (WOUT / TW));   // 4096
    dim3 block(256);

    if (use_xt) {
        hipLaunchKernelGGL(prep_xt, dim3(B_ * HIN * (WIN/64)), dim3(256), 0, stream, x, xTp);
        hipLaunchKernelGGL(fused_main, grid, block, 0, stream,
                           r, W1, b1, w2t, b2, wcb, bc, xTp, out);
    } else {
        hipLaunchKernelGGL(fused_fb, grid, block, 0, stream,
                           x, r, W1, b1, w2t, b2, wcb, bc, out);
    }
}